// Round 1
// baseline (750.416 us; speedup 1.0000x reference)
//
#include <hip/hip_runtime.h>
#include <math.h>

#define N_NODES 50000
#define N_EDGES 800000
#define D 128
#define L 3
#define SLOPE 0.2f
#define LN_EPS 1e-5f
#define ETOT (N_EDGES + N_NODES)

// ---------------- CSR build (once per call, reused for all layers) ----------

__global__ void hist_kernel(const int* __restrict__ ei, int* __restrict__ counts) {
    int idx = blockIdx.x * blockDim.x + threadIdx.x;
    if (idx >= ETOT) return;
    int d = (idx < N_EDGES) ? ei[N_EDGES + idx] : (idx - N_EDGES);
    atomicAdd(&counts[d], 1);
}

// single-block exclusive scan over N_NODES counts -> offsets[N_NODES+1]
__global__ void scan_kernel(const int* __restrict__ counts, int* __restrict__ offsets) {
    __shared__ int tmp[1024];
    int tid = threadIdx.x;
    int carry = 0;
    for (int base = 0; base < N_NODES; base += 1024) {
        int i = base + tid;
        int v = (i < N_NODES) ? counts[i] : 0;
        __syncthreads();              // protect tmp from previous chunk readers
        tmp[tid] = v;
        __syncthreads();
        for (int off = 1; off < 1024; off <<= 1) {
            int u = (tid >= off) ? tmp[tid - off] : 0;
            __syncthreads();
            tmp[tid] += u;
            __syncthreads();
        }
        if (i < N_NODES) offsets[i] = carry + tmp[tid] - v;   // exclusive
        carry += tmp[1023];
    }
    if (tid == 0) offsets[N_NODES] = carry;
}

__global__ void scatter_kernel(const int* __restrict__ ei, const int* __restrict__ offsets,
                               int* __restrict__ cursor, int* __restrict__ sorted_src) {
    int idx = blockIdx.x * blockDim.x + threadIdx.x;
    if (idx >= ETOT) return;
    int s, d;
    if (idx < N_EDGES) { s = ei[idx]; d = ei[N_EDGES + idx]; }
    else               { s = d = idx - N_EDGES; }
    int pos = offsets[d] + atomicAdd(&cursor[d], 1);
    sorted_src[pos] = s;
}

// ---------------- fused dual GEMM: xl = h@Wl, xr = h@Wr --------------------
// block: 256 threads, 64 rows x 256 cols (Wl cols 0..127 | Wr cols 0..127)

__global__ __launch_bounds__(256) void gemm2_kernel(
        const float* __restrict__ h, const float* __restrict__ Wl,
        const float* __restrict__ Wr, float* __restrict__ xl, float* __restrict__ xr) {
    __shared__ float As[64][D];   // 32 KB
    int t = threadIdx.x;
    int row0 = blockIdx.x * 64;
    // stage the 64x128 h tile, coalesced float4
    for (int i = t; i < 64 * (D / 4); i += 256) {
        int r  = i >> 5;            // 32 float4 per row
        int c4 = (i & 31) << 2;
        int row = row0 + r;
        float4 v = make_float4(0.f, 0.f, 0.f, 0.f);
        if (row < N_NODES) v = *(const float4*)&h[(size_t)row * D + c4];
        *(float4*)&As[r][c4] = v;
    }
    __syncthreads();
    int tx = t & 63;                // col group: cols 4*tx .. 4*tx+3 of 256
    int ty = t >> 6;                // row group: rows ty*16 .. ty*16+15
    int c = tx << 2;
    const float* W = (c < D) ? (Wl + c) : (Wr + (c - D));
    float acc[16][4];
    #pragma unroll
    for (int r = 0; r < 16; ++r) { acc[r][0] = acc[r][1] = acc[r][2] = acc[r][3] = 0.f; }
    #pragma unroll 4
    for (int k = 0; k < D; ++k) {
        float4 w = *(const float4*)&W[k * D];
        #pragma unroll
        for (int r = 0; r < 16; ++r) {
            float a = As[ty * 16 + r][k];   // wave-uniform broadcast
            acc[r][0] = fmaf(a, w.x, acc[r][0]);
            acc[r][1] = fmaf(a, w.y, acc[r][1]);
            acc[r][2] = fmaf(a, w.z, acc[r][2]);
            acc[r][3] = fmaf(a, w.w, acc[r][3]);
        }
    }
    float* out = (c < D) ? (xl + c) : (xr + (c - D));
    #pragma unroll
    for (int r = 0; r < 16; ++r) {
        int row = row0 + ty * 16 + r;
        if (row < N_NODES)
            *(float4*)&out[(size_t)row * D] =
                make_float4(acc[r][0], acc[r][1], acc[r][2], acc[r][3]);
    }
}

// ---------------- per-node GATv2 + softmax + LN + ELU + residual -----------
// one wave (64 lanes) per node; lane holds channels {2*lane, 2*lane+1}
// head(2*lane) = lane>>3  (C=16 -> a float2 never spans heads)

__global__ __launch_bounds__(256) void gat_node_kernel(
        const float* __restrict__ xl, const float* __restrict__ xr,
        const int* __restrict__ offsets, const int* __restrict__ sorted_src,
        const float* __restrict__ att_l, const float* __restrict__ bias_l,
        const float* __restrict__ gamma_l, const float* __restrict__ beta_l,
        float* __restrict__ hio) {
    int wave = (blockIdx.x * blockDim.x + threadIdx.x) >> 6;
    if (wave >= N_NODES) return;
    int lane = threadIdx.x & 63;
    int node = wave;
    size_t di = (size_t)node * D + 2 * lane;
    float2 xrv  = *(const float2*)&xr[di];
    float2 attv = *(const float2*)&att_l[2 * lane];
    float m = -1e30f, s = 0.f;
    float accx = 0.f, accy = 0.f;
    int beg = offsets[node], end = offsets[node + 1];
    for (int i = beg; i < end; ++i) {
        int src = sorted_src[i];
        float2 xlv = *(const float2*)&xl[(size_t)src * D + 2 * lane];
        float f0 = xlv.x + xrv.x, f1 = xlv.y + xrv.y;
        float l0 = f0 > 0.f ? f0 : SLOPE * f0;
        float l1 = f1 > 0.f ? f1 : SLOPE * f1;
        float p = l0 * attv.x + l1 * attv.y;
        p += __shfl_xor(p, 1);          // reduce 16 channels of this head
        p += __shfl_xor(p, 2);
        p += __shfl_xor(p, 4);
        // online softmax update
        float mn = fmaxf(m, p);
        float sc = __expf(m - mn);
        float e  = __expf(p - mn);
        s    = s * sc + e;
        accx = accx * sc + e * xlv.x;
        accy = accy * sc + e * xlv.y;
        m = mn;
    }
    float inv = 1.f / s;                // every node has >=1 edge (self-loop)
    float2 bia = *(const float2*)&bias_l[2 * lane];
    float o0 = accx * inv + bia.x;
    float o1 = accy * inv + bia.y;
    // LayerNorm over 128 channels (full-wave reduction)
    float sum = o0 + o1, sq = o0 * o0 + o1 * o1;
    #pragma unroll
    for (int msk = 1; msk < 64; msk <<= 1) {
        sum += __shfl_xor(sum, msk);
        sq  += __shfl_xor(sq, msk);
    }
    float mu   = sum * (1.f / 128.f);
    float var  = sq * (1.f / 128.f) - mu * mu;
    float rstd = rsqrtf(var + LN_EPS);
    float2 gam = *(const float2*)&gamma_l[2 * lane];
    float2 bet = *(const float2*)&beta_l[2 * lane];
    float y0 = (o0 - mu) * rstd * gam.x + bet.x;
    float y1 = (o1 - mu) * rstd * gam.y + bet.y;
    // ELU (alpha=1)
    y0 = y0 > 0.f ? y0 : __expf(y0) - 1.f;
    y1 = y1 > 0.f ? y1 : __expf(y1) - 1.f;
    // residual, in-place on h
    float2 hv = *(const float2*)&hio[di];
    hv.x += y0; hv.y += y1;
    *(float2*)&hio[di] = hv;
}

// ---------------------------------------------------------------------------

extern "C" void kernel_launch(void* const* d_in, const int* in_sizes, int n_in,
                              void* d_out, int out_size, void* d_ws, size_t ws_size,
                              hipStream_t stream) {
    const float* x     = (const float*)d_in[0];
    const float* Wl    = (const float*)d_in[1];
    const float* Wr    = (const float*)d_in[2];
    const float* att   = (const float*)d_in[3];
    const float* bias  = (const float*)d_in[4];
    const float* gamma = (const float*)d_in[5];
    const float* beta  = (const float*)d_in[6];
    const int*   ei    = (const int*)d_in[7];
    float* h = (float*)d_out;

    char* ws = (char*)d_ws;
    float* xl = (float*)ws;          ws += (size_t)N_NODES * D * sizeof(float);
    float* xr = (float*)ws;          ws += (size_t)N_NODES * D * sizeof(float);
    int* offsets = (int*)ws;         ws += (size_t)(N_NODES + 4) * sizeof(int);
    int* counts  = (int*)ws;         ws += (size_t)N_NODES * sizeof(int);
    int* sorted_src = (int*)ws;      // ETOT ints

    // h := x
    hipMemcpyAsync(h, x, (size_t)N_NODES * D * sizeof(float),
                   hipMemcpyDeviceToDevice, stream);

    // CSR by dst (shared by all 3 layers)
    hipMemsetAsync(counts, 0, (size_t)N_NODES * sizeof(int), stream);
    hist_kernel<<<(ETOT + 255) / 256, 256, 0, stream>>>(ei, counts);
    scan_kernel<<<1, 1024, 0, stream>>>(counts, offsets);
    hipMemsetAsync(counts, 0, (size_t)N_NODES * sizeof(int), stream);  // reuse as cursor
    scatter_kernel<<<(ETOT + 255) / 256, 256, 0, stream>>>(ei, offsets, counts, sorted_src);

    for (int l = 0; l < L; ++l) {
        gemm2_kernel<<<(N_NODES + 63) / 64, 256, 0, stream>>>(
            h, Wl + (size_t)l * D * D, Wr + (size_t)l * D * D, xl, xr);
        gat_node_kernel<<<(N_NODES * 64 + 255) / 256, 256, 0, stream>>>(
            xl, xr, offsets, sorted_src,
            att + (size_t)l * D, bias + (size_t)l * D,
            gamma + (size_t)l * D, beta + (size_t)l * D, h);
    }
}

// Round 2
// 570.417 us; speedup vs baseline: 1.3156x; 1.3156x over previous
//
#include <hip/hip_runtime.h>
#include <math.h>

#define N_NODES 50000
#define N_EDGES 800000
#define D 128
#define L 3
#define SLOPE 0.2f
#define LN_EPS 1e-5f
#define ETOT (N_EDGES + N_NODES)

// ---------------- CSR build (once per call, reused for all layers) ----------

__global__ void hist_kernel(const int* __restrict__ ei, int* __restrict__ counts) {
    int idx = blockIdx.x * blockDim.x + threadIdx.x;
    if (idx >= ETOT) return;
    int d = (idx < N_EDGES) ? ei[N_EDGES + idx] : (idx - N_EDGES);
    atomicAdd(&counts[d], 1);
}

// single-block exclusive scan, shfl-based (3 syncs per 1024-chunk)
__global__ __launch_bounds__(1024) void scan_kernel(const int* __restrict__ counts,
                                                    int* __restrict__ offsets) {
    __shared__ int wsum[16];
    int tid = threadIdx.x;
    int lane = tid & 63, w = tid >> 6;
    int carry = 0;
    for (int base = 0; base < N_NODES; base += 1024) {
        int i = base + tid;
        int v = (i < N_NODES) ? counts[i] : 0;
        // inclusive wave scan
        int sc = v;
        #pragma unroll
        for (int off = 1; off < 64; off <<= 1) {
            int u = __shfl_up(sc, off);
            if (lane >= off) sc += u;
        }
        if (lane == 63) wsum[w] = sc;
        __syncthreads();
        if (w == 0) {
            int t2 = (lane < 16) ? wsum[lane] : 0;
            #pragma unroll
            for (int off = 1; off < 16; off <<= 1) {
                int u = __shfl_up(t2, off);
                if (lane >= off) t2 += u;
            }
            if (lane < 16) wsum[lane] = t2;
        }
        __syncthreads();
        int wpref = (w == 0) ? 0 : wsum[w - 1];
        if (i < N_NODES) offsets[i] = carry + wpref + sc - v;   // exclusive
        carry += wsum[15];
        __syncthreads();          // protect wsum before next chunk overwrites
    }
    if (tid == 0) offsets[N_NODES] = carry;
}

__global__ void scatter_kernel(const int* __restrict__ ei, const int* __restrict__ offsets,
                               int* __restrict__ cursor, int* __restrict__ sorted_src) {
    int idx = blockIdx.x * blockDim.x + threadIdx.x;
    if (idx >= ETOT) return;
    int s, d;
    if (idx < N_EDGES) { s = ei[idx]; d = ei[N_EDGES + idx]; }
    else               { s = d = idx - N_EDGES; }
    int pos = offsets[d] + atomicAdd(&cursor[d], 1);
    sorted_src[pos] = s;
}

// ---------------- fused dual GEMM: xl = h@Wl, xr = h@Wr --------------------
// block: 256 threads, 64 rows x 256 cols (Wl cols 0..127 | Wr cols 0..127)
// k unrolled x4: As read as float4 (ds_read_b128), 4 W float4 loads hoisted.

__global__ __launch_bounds__(256) void gemm2_kernel(
        const float* __restrict__ h, const float* __restrict__ Wl,
        const float* __restrict__ Wr, float* __restrict__ xl, float* __restrict__ xr) {
    __shared__ float As[64][D];   // 32 KB
    int t = threadIdx.x;
    int row0 = blockIdx.x * 64;
    for (int i = t; i < 64 * (D / 4); i += 256) {
        int r  = i >> 5;
        int c4 = (i & 31) << 2;
        int row = row0 + r;
        float4 v = make_float4(0.f, 0.f, 0.f, 0.f);
        if (row < N_NODES) v = *(const float4*)&h[(size_t)row * D + c4];
        *(float4*)&As[r][c4] = v;
    }
    __syncthreads();
    int tx = t & 63;
    int ty = t >> 6;
    int c = tx << 2;
    const float* W = (c < D) ? (Wl + c) : (Wr + (c - D));
    float acc[16][4];
    #pragma unroll
    for (int r = 0; r < 16; ++r) { acc[r][0] = acc[r][1] = acc[r][2] = acc[r][3] = 0.f; }
    for (int k0 = 0; k0 < D; k0 += 4) {
        float4 w0 = *(const float4*)&W[(k0 + 0) * D];
        float4 w1 = *(const float4*)&W[(k0 + 1) * D];
        float4 w2 = *(const float4*)&W[(k0 + 2) * D];
        float4 w3 = *(const float4*)&W[(k0 + 3) * D];
        #pragma unroll
        for (int r = 0; r < 16; ++r) {
            float4 a = *(const float4*)&As[ty * 16 + r][k0];   // wave-uniform b128
            acc[r][0] = fmaf(a.x, w0.x, acc[r][0]);
            acc[r][1] = fmaf(a.x, w0.y, acc[r][1]);
            acc[r][2] = fmaf(a.x, w0.z, acc[r][2]);
            acc[r][3] = fmaf(a.x, w0.w, acc[r][3]);
            acc[r][0] = fmaf(a.y, w1.x, acc[r][0]);
            acc[r][1] = fmaf(a.y, w1.y, acc[r][1]);
            acc[r][2] = fmaf(a.y, w1.z, acc[r][2]);
            acc[r][3] = fmaf(a.y, w1.w, acc[r][3]);
            acc[r][0] = fmaf(a.z, w2.x, acc[r][0]);
            acc[r][1] = fmaf(a.z, w2.y, acc[r][1]);
            acc[r][2] = fmaf(a.z, w2.z, acc[r][2]);
            acc[r][3] = fmaf(a.z, w2.w, acc[r][3]);
            acc[r][0] = fmaf(a.w, w3.x, acc[r][0]);
            acc[r][1] = fmaf(a.w, w3.y, acc[r][1]);
            acc[r][2] = fmaf(a.w, w3.z, acc[r][2]);
            acc[r][3] = fmaf(a.w, w3.w, acc[r][3]);
        }
    }
    float* out = (c < D) ? (xl + c) : (xr + (c - D));
    #pragma unroll
    for (int r = 0; r < 16; ++r) {
        int row = row0 + ty * 16 + r;
        if (row < N_NODES)
            *(float4*)&out[(size_t)row * D] =
                make_float4(acc[r][0], acc[r][1], acc[r][2], acc[r][3]);
    }
}

// ---------------- per-node GATv2 + softmax + LN + ELU + residual -----------
// one wave per node; lane holds channels {2*lane, 2*lane+1}; head = lane>>3.
// Edge indices preloaded 64-wide, broadcast via readlane; 4 edges/iteration.

__global__ __launch_bounds__(256) void gat_node_kernel(
        const float* __restrict__ xl, const float* __restrict__ xr,
        const int* __restrict__ offsets, const int* __restrict__ sorted_src,
        const float* __restrict__ att_l, const float* __restrict__ bias_l,
        const float* __restrict__ gamma_l, const float* __restrict__ beta_l,
        const float* __restrict__ hin, float* __restrict__ hout) {
    int node = (blockIdx.x * blockDim.x + threadIdx.x) >> 6;
    if (node >= N_NODES) return;
    int lane = threadIdx.x & 63;
    size_t di = (size_t)node * D + 2 * lane;
    float2 xrv  = *(const float2*)&xr[di];
    float2 attv = *(const float2*)&att_l[2 * lane];
    int beg = offsets[node], end = offsets[node + 1];
    float m = -1e30f, s = 0.f, accx = 0.f, accy = 0.f;
    for (int c0 = beg; c0 < end; c0 += 64) {
        int cnt = end - c0; if (cnt > 64) cnt = 64;
        int idx = sorted_src[c0 + (lane < cnt ? lane : cnt - 1)];   // coalesced
        int j = 0;
        for (; j + 4 <= cnt; j += 4) {
            int s0 = __builtin_amdgcn_readlane(idx, j);
            int s1 = __builtin_amdgcn_readlane(idx, j + 1);
            int s2 = __builtin_amdgcn_readlane(idx, j + 2);
            int s3 = __builtin_amdgcn_readlane(idx, j + 3);
            float2 v0 = *(const float2*)&xl[(size_t)s0 * D + 2 * lane];
            float2 v1 = *(const float2*)&xl[(size_t)s1 * D + 2 * lane];
            float2 v2 = *(const float2*)&xl[(size_t)s2 * D + 2 * lane];
            float2 v3 = *(const float2*)&xl[(size_t)s3 * D + 2 * lane];
            float f, g, p0, p1, p2, p3;
            f = v0.x + xrv.x; g = v0.y + xrv.y;
            p0 = (f > 0.f ? f : SLOPE * f) * attv.x + (g > 0.f ? g : SLOPE * g) * attv.y;
            f = v1.x + xrv.x; g = v1.y + xrv.y;
            p1 = (f > 0.f ? f : SLOPE * f) * attv.x + (g > 0.f ? g : SLOPE * g) * attv.y;
            f = v2.x + xrv.x; g = v2.y + xrv.y;
            p2 = (f > 0.f ? f : SLOPE * f) * attv.x + (g > 0.f ? g : SLOPE * g) * attv.y;
            f = v3.x + xrv.x; g = v3.y + xrv.y;
            p3 = (f > 0.f ? f : SLOPE * f) * attv.x + (g > 0.f ? g : SLOPE * g) * attv.y;
            p0 += __shfl_xor(p0, 1); p1 += __shfl_xor(p1, 1);
            p2 += __shfl_xor(p2, 1); p3 += __shfl_xor(p3, 1);
            p0 += __shfl_xor(p0, 2); p1 += __shfl_xor(p1, 2);
            p2 += __shfl_xor(p2, 2); p3 += __shfl_xor(p3, 2);
            p0 += __shfl_xor(p0, 4); p1 += __shfl_xor(p1, 4);
            p2 += __shfl_xor(p2, 4); p3 += __shfl_xor(p3, 4);
            float mx = fmaxf(fmaxf(p0, p1), fmaxf(p2, p3));
            float mn = fmaxf(m, mx);
            float scl = __expf(m - mn);
            float e0 = __expf(p0 - mn), e1 = __expf(p1 - mn);
            float e2 = __expf(p2 - mn), e3 = __expf(p3 - mn);
            s    = s    * scl + ((e0 + e1) + (e2 + e3));
            accx = accx * scl + ((e0 * v0.x + e1 * v1.x) + (e2 * v2.x + e3 * v3.x));
            accy = accy * scl + ((e0 * v0.y + e1 * v1.y) + (e2 * v2.y + e3 * v3.y));
            m = mn;
        }
        for (; j < cnt; ++j) {
            int s0 = __builtin_amdgcn_readlane(idx, j);
            float2 v0 = *(const float2*)&xl[(size_t)s0 * D + 2 * lane];
            float f = v0.x + xrv.x, g = v0.y + xrv.y;
            float p0 = (f > 0.f ? f : SLOPE * f) * attv.x + (g > 0.f ? g : SLOPE * g) * attv.y;
            p0 += __shfl_xor(p0, 1);
            p0 += __shfl_xor(p0, 2);
            p0 += __shfl_xor(p0, 4);
            float mn = fmaxf(m, p0);
            float scl = __expf(m - mn);
            float e = __expf(p0 - mn);
            s    = s    * scl + e;
            accx = accx * scl + e * v0.x;
            accy = accy * scl + e * v0.y;
            m = mn;
        }
    }
    float inv = 1.f / s;                // every node has >=1 edge (self-loop)
    float2 bia = *(const float2*)&bias_l[2 * lane];
    float o0 = accx * inv + bia.x;
    float o1 = accy * inv + bia.y;
    float sum = o0 + o1, sq = o0 * o0 + o1 * o1;
    #pragma unroll
    for (int msk = 1; msk < 64; msk <<= 1) {
        sum += __shfl_xor(sum, msk);
        sq  += __shfl_xor(sq, msk);
    }
    float mu   = sum * (1.f / 128.f);
    float var  = sq * (1.f / 128.f) - mu * mu;
    float rstd = rsqrtf(var + LN_EPS);
    float2 gam = *(const float2*)&gamma_l[2 * lane];
    float2 bet = *(const float2*)&beta_l[2 * lane];
    float y0 = (o0 - mu) * rstd * gam.x + bet.x;
    float y1 = (o1 - mu) * rstd * gam.y + bet.y;
    y0 = y0 > 0.f ? y0 : __expf(y0) - 1.f;      // ELU (alpha=1)
    y1 = y1 > 0.f ? y1 : __expf(y1) - 1.f;
    float2 hv = *(const float2*)&hin[di];
    hv.x += y0; hv.y += y1;
    *(float2*)&hout[di] = hv;
}

// ---------------------------------------------------------------------------

extern "C" void kernel_launch(void* const* d_in, const int* in_sizes, int n_in,
                              void* d_out, int out_size, void* d_ws, size_t ws_size,
                              hipStream_t stream) {
    const float* x     = (const float*)d_in[0];
    const float* Wl    = (const float*)d_in[1];
    const float* Wr    = (const float*)d_in[2];
    const float* att   = (const float*)d_in[3];
    const float* bias  = (const float*)d_in[4];
    const float* gamma = (const float*)d_in[5];
    const float* beta  = (const float*)d_in[6];
    const int*   ei    = (const int*)d_in[7];
    float* h = (float*)d_out;

    char* ws = (char*)d_ws;
    float* xl = (float*)ws;          ws += (size_t)N_NODES * D * sizeof(float);
    float* xr = (float*)ws;          ws += (size_t)N_NODES * D * sizeof(float);
    int* offsets = (int*)ws;         ws += (size_t)(N_NODES + 4) * sizeof(int);
    int* counts  = (int*)ws;         ws += (size_t)N_NODES * sizeof(int);
    int* sorted_src = (int*)ws;      // ETOT ints

    // CSR by dst (shared by all 3 layers)
    hipMemsetAsync(counts, 0, (size_t)N_NODES * sizeof(int), stream);
    hist_kernel<<<(ETOT + 255) / 256, 256, 0, stream>>>(ei, counts);
    scan_kernel<<<1, 1024, 0, stream>>>(counts, offsets);
    hipMemsetAsync(counts, 0, (size_t)N_NODES * sizeof(int), stream);  // reuse as cursor
    scatter_kernel<<<(ETOT + 255) / 256, 256, 0, stream>>>(ei, offsets, counts, sorted_src);

    for (int l = 0; l < L; ++l) {
        const float* hin = (l == 0) ? x : h;
        gemm2_kernel<<<(N_NODES + 63) / 64, 256, 0, stream>>>(
            hin, Wl + (size_t)l * D * D, Wr + (size_t)l * D * D, xl, xr);
        gat_node_kernel<<<(N_NODES * 64 + 255) / 256, 256, 0, stream>>>(
            xl, xr, offsets, sorted_src,
            att + (size_t)l * D, bias + (size_t)l * D,
            gamma + (size_t)l * D, beta + (size_t)l * D, hin, h);
    }
}

// Round 3
// 518.770 us; speedup vs baseline: 1.4465x; 1.0996x over previous
//
#include <hip/hip_runtime.h>
#include <math.h>

#define N_NODES 50000
#define N_EDGES 800000
#define D 128
#define L 3
#define SLOPE 0.2f
#define LN_EPS 1e-5f
#define ETOT (N_EDGES + N_NODES)
#define SCAN_BLOCKS ((N_NODES + 1023) / 1024)   // 49

// ---------------- CSR build (once per call, reused for all layers) ----------

__global__ void hist_kernel(const int* __restrict__ ei, int* __restrict__ counts) {
    int idx = blockIdx.x * blockDim.x + threadIdx.x;
    if (idx >= ETOT) return;
    int d = (idx < N_EDGES) ? ei[N_EDGES + idx] : (idx - N_EDGES);
    atomicAdd(&counts[d], 1);
}

// hierarchical scan, stage 1: per-block exclusive scan + block sums
__global__ __launch_bounds__(1024) void scan1_kernel(const int* __restrict__ counts,
                                                     int* __restrict__ offsets,
                                                     int* __restrict__ bsum) {
    __shared__ int wsum[16];
    int tid = threadIdx.x;
    int lane = tid & 63, w = tid >> 6;
    int i = blockIdx.x * 1024 + tid;
    int v = (i < N_NODES) ? counts[i] : 0;
    int sc = v;
    #pragma unroll
    for (int off = 1; off < 64; off <<= 1) {
        int u = __shfl_up(sc, off);
        if (lane >= off) sc += u;
    }
    if (lane == 63) wsum[w] = sc;
    __syncthreads();
    if (w == 0) {
        int t2 = (lane < 16) ? wsum[lane] : 0;
        #pragma unroll
        for (int off = 1; off < 16; off <<= 1) {
            int u = __shfl_up(t2, off);
            if (lane >= off) t2 += u;
        }
        if (lane < 16) wsum[lane] = t2;
    }
    __syncthreads();
    int wpref = (w == 0) ? 0 : wsum[w - 1];
    if (i < N_NODES) offsets[i] = wpref + sc - v;      // block-local exclusive
    if (tid == 0) bsum[blockIdx.x] = wsum[15];
}

// stage 2: single wave scans the 49 block sums -> exclusive block prefixes
__global__ __launch_bounds__(64) void scan2_kernel(const int* __restrict__ bsum,
                                                   int* __restrict__ bpre) {
    int lane = threadIdx.x;
    int v = (lane < SCAN_BLOCKS) ? bsum[lane] : 0;
    int sc = v;
    #pragma unroll
    for (int off = 1; off < 64; off <<= 1) {
        int u = __shfl_up(sc, off);
        if (lane >= off) sc += u;
    }
    if (lane < SCAN_BLOCKS) bpre[lane] = sc - v;       // exclusive
}

// stage 3: add block prefix in-place; write sentinel
__global__ __launch_bounds__(1024) void scan3_kernel(int* __restrict__ offsets,
                                                     const int* __restrict__ bpre) {
    int i = blockIdx.x * 1024 + threadIdx.x;
    if (i < N_NODES) offsets[i] += bpre[blockIdx.x];
    if (i == 0) offsets[N_NODES] = ETOT;
}

__global__ void scatter_kernel(const int* __restrict__ ei, const int* __restrict__ offsets,
                               int* __restrict__ cursor, int* __restrict__ sorted_src) {
    int idx = blockIdx.x * blockDim.x + threadIdx.x;
    if (idx >= ETOT) return;
    int s, d;
    if (idx < N_EDGES) { s = ei[idx]; d = ei[N_EDGES + idx]; }
    else               { s = d = idx - N_EDGES; }
    int pos = offsets[d] + atomicAdd(&cursor[d], 1);
    sorted_src[pos] = s;
}

// ---------------- fused dual GEMM: xl = h@Wl, xr = h@Wr --------------------

__global__ __launch_bounds__(256) void gemm2_kernel(
        const float* __restrict__ h, const float* __restrict__ Wl,
        const float* __restrict__ Wr, float* __restrict__ xl, float* __restrict__ xr) {
    __shared__ float As[64][D];   // 32 KB
    int t = threadIdx.x;
    int row0 = blockIdx.x * 64;
    for (int i = t; i < 64 * (D / 4); i += 256) {
        int r  = i >> 5;
        int c4 = (i & 31) << 2;
        int row = row0 + r;
        float4 v = make_float4(0.f, 0.f, 0.f, 0.f);
        if (row < N_NODES) v = *(const float4*)&h[(size_t)row * D + c4];
        *(float4*)&As[r][c4] = v;
    }
    __syncthreads();
    int tx = t & 63;
    int ty = t >> 6;
    int c = tx << 2;
    const float* W = (c < D) ? (Wl + c) : (Wr + (c - D));
    float acc[16][4];
    #pragma unroll
    for (int r = 0; r < 16; ++r) { acc[r][0] = acc[r][1] = acc[r][2] = acc[r][3] = 0.f; }
    for (int k0 = 0; k0 < D; k0 += 4) {
        float4 w0 = *(const float4*)&W[(k0 + 0) * D];
        float4 w1 = *(const float4*)&W[(k0 + 1) * D];
        float4 w2 = *(const float4*)&W[(k0 + 2) * D];
        float4 w3 = *(const float4*)&W[(k0 + 3) * D];
        #pragma unroll
        for (int r = 0; r < 16; ++r) {
            float4 a = *(const float4*)&As[ty * 16 + r][k0];   // wave-uniform b128
            acc[r][0] = fmaf(a.x, w0.x, acc[r][0]);
            acc[r][1] = fmaf(a.x, w0.y, acc[r][1]);
            acc[r][2] = fmaf(a.x, w0.z, acc[r][2]);
            acc[r][3] = fmaf(a.x, w0.w, acc[r][3]);
            acc[r][0] = fmaf(a.y, w1.x, acc[r][0]);
            acc[r][1] = fmaf(a.y, w1.y, acc[r][1]);
            acc[r][2] = fmaf(a.y, w1.z, acc[r][2]);
            acc[r][3] = fmaf(a.y, w1.w, acc[r][3]);
            acc[r][0] = fmaf(a.z, w2.x, acc[r][0]);
            acc[r][1] = fmaf(a.z, w2.y, acc[r][1]);
            acc[r][2] = fmaf(a.z, w2.z, acc[r][2]);
            acc[r][3] = fmaf(a.z, w2.w, acc[r][3]);
            acc[r][0] = fmaf(a.w, w3.x, acc[r][0]);
            acc[r][1] = fmaf(a.w, w3.y, acc[r][1]);
            acc[r][2] = fmaf(a.w, w3.z, acc[r][2]);
            acc[r][3] = fmaf(a.w, w3.w, acc[r][3]);
        }
    }
    float* out = (c < D) ? (xl + c) : (xr + (c - D));
    #pragma unroll
    for (int r = 0; r < 16; ++r) {
        int row = row0 + ty * 16 + r;
        if (row < N_NODES)
            *(float4*)&out[(size_t)row * D] =
                make_float4(acc[r][0], acc[r][1], acc[r][2], acc[r][3]);
    }
}

// ---------------- per-node GATv2 + softmax + LN + ELU + residual -----------
// one wave per node; lane holds channels {2*lane, 2*lane+1}; head = lane>>3.
// No max-subtraction (logits bounded << 88); DPP 8-lane head reduction.

__device__ __forceinline__ float head_reduce8(float p) {
    // sum across the 8 lanes of a head (lanes grouped 8-aligned): all-VALU DPP
    int t;
    t = __builtin_amdgcn_update_dpp(0, __float_as_int(p), 0xB1, 0xF, 0xF, true);  // quad_perm [1,0,3,2] : xor 1
    p += __int_as_float(t);
    t = __builtin_amdgcn_update_dpp(0, __float_as_int(p), 0x4E, 0xF, 0xF, true);  // quad_perm [2,3,0,1] : xor 2
    p += __int_as_float(t);
    t = __builtin_amdgcn_update_dpp(0, __float_as_int(p), 0x141, 0xF, 0xF, true); // row_half_mirror : xor 4 (quad-uniform)
    p += __int_as_float(t);
    return p;
}

__device__ __forceinline__ float leaky(float f) { return fmaxf(f, SLOPE * f); }

__global__ __launch_bounds__(256) void gat_node_kernel(
        const float* __restrict__ xl, const float* __restrict__ xr,
        const int* __restrict__ offsets, const int* __restrict__ sorted_src,
        const float* __restrict__ att_l, const float* __restrict__ bias_l,
        const float* __restrict__ gamma_l, const float* __restrict__ beta_l,
        const float* __restrict__ hin, float* __restrict__ hout) {
    int node = (blockIdx.x * blockDim.x + threadIdx.x) >> 6;
    if (node >= N_NODES) return;
    int lane = threadIdx.x & 63;
    unsigned laneoff = lane * 8u;               // byte offset of this lane's float2
    size_t di = (size_t)node * D + 2 * lane;
    float2 xrv  = *(const float2*)&xr[di];
    float2 attv = *(const float2*)&att_l[2 * lane];
    int beg = offsets[node], end = offsets[node + 1];
    float s = 0.f, accx = 0.f, accy = 0.f;
    const char* xlb = (const char*)xl;
    for (int c0 = beg; c0 < end; c0 += 64) {
        int cnt = end - c0; if (cnt > 64) cnt = 64;
        int idx = sorted_src[c0 + (lane < cnt ? lane : cnt - 1)];   // coalesced
        unsigned off = (unsigned)idx << 9;       // byte offset of row (128*4B)
        int j = 0;
        for (; j + 4 <= cnt; j += 4) {
            unsigned o0 = __builtin_amdgcn_readlane(off, j)     + laneoff;
            unsigned o1 = __builtin_amdgcn_readlane(off, j + 1) + laneoff;
            unsigned o2 = __builtin_amdgcn_readlane(off, j + 2) + laneoff;
            unsigned o3 = __builtin_amdgcn_readlane(off, j + 3) + laneoff;
            float2 v0 = *(const float2*)(xlb + o0);
            float2 v1 = *(const float2*)(xlb + o1);
            float2 v2 = *(const float2*)(xlb + o2);
            float2 v3 = *(const float2*)(xlb + o3);
            float p0 = fmaf(leaky(v0.x + xrv.x), attv.x, leaky(v0.y + xrv.y) * attv.y);
            float p1 = fmaf(leaky(v1.x + xrv.x), attv.x, leaky(v1.y + xrv.y) * attv.y);
            float p2 = fmaf(leaky(v2.x + xrv.x), attv.x, leaky(v2.y + xrv.y) * attv.y);
            float p3 = fmaf(leaky(v3.x + xrv.x), attv.x, leaky(v3.y + xrv.y) * attv.y);
            p0 = head_reduce8(p0);
            p1 = head_reduce8(p1);
            p2 = head_reduce8(p2);
            p3 = head_reduce8(p3);
            float e0 = __expf(p0), e1 = __expf(p1);
            float e2 = __expf(p2), e3 = __expf(p3);
            s += (e0 + e1) + (e2 + e3);
            accx = fmaf(e0, v0.x, accx); accy = fmaf(e0, v0.y, accy);
            accx = fmaf(e1, v1.x, accx); accy = fmaf(e1, v1.y, accy);
            accx = fmaf(e2, v2.x, accx); accy = fmaf(e2, v2.y, accy);
            accx = fmaf(e3, v3.x, accx); accy = fmaf(e3, v3.y, accy);
        }
        for (; j < cnt; ++j) {
            unsigned o0 = __builtin_amdgcn_readlane(off, j) + laneoff;
            float2 v0 = *(const float2*)(xlb + o0);
            float p0 = fmaf(leaky(v0.x + xrv.x), attv.x, leaky(v0.y + xrv.y) * attv.y);
            p0 = head_reduce8(p0);
            float e0 = __expf(p0);
            s += e0;
            accx = fmaf(e0, v0.x, accx);
            accy = fmaf(e0, v0.y, accy);
        }
    }
    float inv = 1.f / s;                // every node has >=1 edge (self-loop)
    float2 bia = *(const float2*)&bias_l[2 * lane];
    float o0 = accx * inv + bia.x;
    float o1 = accy * inv + bia.y;
    float sum = o0 + o1, sq = o0 * o0 + o1 * o1;
    #pragma unroll
    for (int msk = 1; msk < 64; msk <<= 1) {
        sum += __shfl_xor(sum, msk);
        sq  += __shfl_xor(sq, msk);
    }
    float mu   = sum * (1.f / 128.f);
    float var  = sq * (1.f / 128.f) - mu * mu;
    float rstd = rsqrtf(var + LN_EPS);
    float2 gam = *(const float2*)&gamma_l[2 * lane];
    float2 bet = *(const float2*)&beta_l[2 * lane];
    float y0 = (o0 - mu) * rstd * gam.x + bet.x;
    float y1 = (o1 - mu) * rstd * gam.y + bet.y;
    y0 = y0 > 0.f ? y0 : __expf(y0) - 1.f;      // ELU (alpha=1)
    y1 = y1 > 0.f ? y1 : __expf(y1) - 1.f;
    float2 hv = *(const float2*)&hin[di];
    hv.x += y0; hv.y += y1;
    *(float2*)&hout[di] = hv;
}

// ---------------------------------------------------------------------------

extern "C" void kernel_launch(void* const* d_in, const int* in_sizes, int n_in,
                              void* d_out, int out_size, void* d_ws, size_t ws_size,
                              hipStream_t stream) {
    const float* x     = (const float*)d_in[0];
    const float* Wl    = (const float*)d_in[1];
    const float* Wr    = (const float*)d_in[2];
    const float* att   = (const float*)d_in[3];
    const float* bias  = (const float*)d_in[4];
    const float* gamma = (const float*)d_in[5];
    const float* beta  = (const float*)d_in[6];
    const int*   ei    = (const int*)d_in[7];
    float* h = (float*)d_out;

    char* ws = (char*)d_ws;
    float* xl = (float*)ws;          ws += (size_t)N_NODES * D * sizeof(float);
    float* xr = (float*)ws;          ws += (size_t)N_NODES * D * sizeof(float);
    int* offsets = (int*)ws;         ws += (size_t)(N_NODES + 4) * sizeof(int);
    int* counts  = (int*)ws;         ws += (size_t)N_NODES * sizeof(int);
    int* bsum    = (int*)ws;         ws += 64 * sizeof(int);
    int* bpre    = (int*)ws;         ws += 64 * sizeof(int);
    int* sorted_src = (int*)ws;      // ETOT ints

    // CSR by dst (shared by all 3 layers)
    hipMemsetAsync(counts, 0, (size_t)N_NODES * sizeof(int), stream);
    hist_kernel<<<(ETOT + 255) / 256, 256, 0, stream>>>(ei, counts);
    scan1_kernel<<<SCAN_BLOCKS, 1024, 0, stream>>>(counts, offsets, bsum);
    scan2_kernel<<<1, 64, 0, stream>>>(bsum, bpre);
    scan3_kernel<<<SCAN_BLOCKS, 1024, 0, stream>>>(offsets, bpre);
    hipMemsetAsync(counts, 0, (size_t)N_NODES * sizeof(int), stream);  // reuse as cursor
    scatter_kernel<<<(ETOT + 255) / 256, 256, 0, stream>>>(ei, offsets, counts, sorted_src);

    for (int l = 0; l < L; ++l) {
        const float* hin = (l == 0) ? x : h;
        gemm2_kernel<<<(N_NODES + 63) / 64, 256, 0, stream>>>(
            hin, Wl + (size_t)l * D * D, Wr + (size_t)l * D * D, xl, xr);
        gat_node_kernel<<<(N_NODES * 64 + 255) / 256, 256, 0, stream>>>(
            xl, xr, offsets, sorted_src,
            att + (size_t)l * D, bias + (size_t)l * D,
            gamma + (size_t)l * D, beta + (size_t)l * D, hin, h);
    }
}

// Round 4
// 453.579 us; speedup vs baseline: 1.6544x; 1.1437x over previous
//
#include <hip/hip_runtime.h>
#include <hip/hip_fp16.h>
#include <math.h>

#define N_NODES 50000
#define N_EDGES 800000
#define D 128
#define L 3
#define SLOPE 0.2f
#define LN_EPS 1e-5f
#define ETOT (N_EDGES + N_NODES)
#define SCAN_BLOCKS ((N_NODES + 1023) / 1024)   // 49

// ---------------- CSR build (once per call, reused for all layers) ----------

__global__ void hist_kernel(const int* __restrict__ ei, int* __restrict__ counts) {
    int idx = blockIdx.x * blockDim.x + threadIdx.x;
    if (idx >= ETOT) return;
    int d = (idx < N_EDGES) ? ei[N_EDGES + idx] : (idx - N_EDGES);
    atomicAdd(&counts[d], 1);
}

__global__ __launch_bounds__(1024) void scan1_kernel(const int* __restrict__ counts,
                                                     int* __restrict__ offsets,
                                                     int* __restrict__ bsum) {
    __shared__ int wsum[16];
    int tid = threadIdx.x;
    int lane = tid & 63, w = tid >> 6;
    int i = blockIdx.x * 1024 + tid;
    int v = (i < N_NODES) ? counts[i] : 0;
    int sc = v;
    #pragma unroll
    for (int off = 1; off < 64; off <<= 1) {
        int u = __shfl_up(sc, off);
        if (lane >= off) sc += u;
    }
    if (lane == 63) wsum[w] = sc;
    __syncthreads();
    if (w == 0) {
        int t2 = (lane < 16) ? wsum[lane] : 0;
        #pragma unroll
        for (int off = 1; off < 16; off <<= 1) {
            int u = __shfl_up(t2, off);
            if (lane >= off) t2 += u;
        }
        if (lane < 16) wsum[lane] = t2;
    }
    __syncthreads();
    int wpref = (w == 0) ? 0 : wsum[w - 1];
    if (i < N_NODES) offsets[i] = wpref + sc - v;      // block-local exclusive
    if (tid == 0) bsum[blockIdx.x] = wsum[15];
}

__global__ __launch_bounds__(64) void scan2_kernel(const int* __restrict__ bsum,
                                                   int* __restrict__ bpre) {
    int lane = threadIdx.x;
    int v = (lane < SCAN_BLOCKS) ? bsum[lane] : 0;
    int sc = v;
    #pragma unroll
    for (int off = 1; off < 64; off <<= 1) {
        int u = __shfl_up(sc, off);
        if (lane >= off) sc += u;
    }
    if (lane < SCAN_BLOCKS) bpre[lane] = sc - v;       // exclusive
}

__global__ __launch_bounds__(1024) void scan3_kernel(int* __restrict__ offsets,
                                                     const int* __restrict__ bpre) {
    int i = blockIdx.x * 1024 + threadIdx.x;
    if (i < N_NODES) offsets[i] += bpre[blockIdx.x];
    if (i == 0) offsets[N_NODES] = ETOT;
}

__global__ void scatter_kernel(const int* __restrict__ ei, const int* __restrict__ offsets,
                               int* __restrict__ cursor, int* __restrict__ sorted_src) {
    int idx = blockIdx.x * blockDim.x + threadIdx.x;
    if (idx >= ETOT) return;
    int s, d;
    if (idx < N_EDGES) { s = ei[idx]; d = ei[N_EDGES + idx]; }
    else               { s = d = idx - N_EDGES; }
    int pos = offsets[d] + atomicAdd(&cursor[d], 1);
    sorted_src[pos] = s;
}

// ---------------- GEMM: out_fp16 = h @ W (one of Wl/Wr per blockIdx.y) -----
// block: 512 threads = 8 waves; wave w -> cols 16w..16w+15; lane -> row.
// A: 1 ds_read_b128 / wave / k0 (row stride 129 dwords: 2-way alias = free).
// W: wave-uniform address (readfirstlane) -> scalar/broadcast loads.

__global__ __launch_bounds__(512) void gemm_half_kernel(
        const float* __restrict__ h, const float* __restrict__ Wl,
        const float* __restrict__ Wr, __half* __restrict__ xlh,
        __half* __restrict__ xrh) {
    __shared__ float As[64][D + 1];   // 33 KB, pad to 129 dwords
    int t = threadIdx.x;
    int row0 = blockIdx.x * 64;
    for (int i = t; i < 64 * (D / 4); i += 512) {
        int r  = i >> 5;
        int c4 = (i & 31) << 2;
        int row = row0 + r;
        float4 v = make_float4(0.f, 0.f, 0.f, 0.f);
        if (row < N_NODES) v = *(const float4*)&h[(size_t)row * D + c4];
        *(float4*)&As[r][c4] = v;
    }
    __syncthreads();
    const float* W   = blockIdx.y ? Wr : Wl;
    __half*      out = blockIdx.y ? xrh : xlh;
    int wv   = __builtin_amdgcn_readfirstlane((int)(threadIdx.x >> 6));
    int lane = threadIdx.x & 63;
    int cw   = wv << 4;                 // col base (uniform)
    const float* Wc = W + cw;
    float acc[16];
    #pragma unroll
    for (int c = 0; c < 16; ++c) acc[c] = 0.f;
    for (int k0 = 0; k0 < D; k0 += 4) {
        float4 wr[4][4];
        #pragma unroll
        for (int kk = 0; kk < 4; ++kk)
            #pragma unroll
            for (int q = 0; q < 4; ++q)
                wr[kk][q] = *(const float4*)&Wc[(k0 + kk) * D + 4 * q];  // uniform
        float4 a = *(const float4*)&As[lane][k0];
        float av[4] = {a.x, a.y, a.z, a.w};
        #pragma unroll
        for (int kk = 0; kk < 4; ++kk) {
            #pragma unroll
            for (int q = 0; q < 4; ++q) {
                acc[4 * q + 0] = fmaf(av[kk], wr[kk][q].x, acc[4 * q + 0]);
                acc[4 * q + 1] = fmaf(av[kk], wr[kk][q].y, acc[4 * q + 1]);
                acc[4 * q + 2] = fmaf(av[kk], wr[kk][q].z, acc[4 * q + 2]);
                acc[4 * q + 3] = fmaf(av[kk], wr[kk][q].w, acc[4 * q + 3]);
            }
        }
    }
    int row = row0 + lane;
    if (row < N_NODES) {
        union { __half2 h2[8]; float4 f4[2]; } u;
        #pragma unroll
        for (int i = 0; i < 8; ++i)
            u.h2[i] = __floats2half2_rn(acc[2 * i], acc[2 * i + 1]);
        float4* dst = (float4*)&out[(size_t)row * D + cw];
        dst[0] = u.f4[0];
        dst[1] = u.f4[1];
    }
}

// ---------------- per-node GATv2 + softmax + LN + ELU + residual -----------
// one wave per node; lane holds channels {2*lane, 2*lane+1}; head = lane>>3.
// xl/xr gathered as fp16 (halves L2/L3 traffic); 8 edges in flight.

__device__ __forceinline__ float head_reduce8(float p) {
    int t;
    t = __builtin_amdgcn_update_dpp(0, __float_as_int(p), 0xB1, 0xF, 0xF, true);  // xor 1
    p += __int_as_float(t);
    t = __builtin_amdgcn_update_dpp(0, __float_as_int(p), 0x4E, 0xF, 0xF, true);  // xor 2
    p += __int_as_float(t);
    t = __builtin_amdgcn_update_dpp(0, __float_as_int(p), 0x141, 0xF, 0xF, true); // xor 4
    p += __int_as_float(t);
    return p;
}

__device__ __forceinline__ float leaky(float f) { return fmaxf(f, SLOPE * f); }

__device__ __forceinline__ float edge_logit(float2 v, float2 xrv, float2 attv) {
    return fmaf(leaky(v.x + xrv.x), attv.x, leaky(v.y + xrv.y) * attv.y);
}

__global__ __launch_bounds__(256) void gat_node_kernel(
        const __half* __restrict__ xlh, const __half* __restrict__ xrh,
        const int* __restrict__ offsets, const int* __restrict__ sorted_src,
        const float* __restrict__ att_l, const float* __restrict__ bias_l,
        const float* __restrict__ gamma_l, const float* __restrict__ beta_l,
        const float* __restrict__ hin, float* __restrict__ hout) {
    int node = (blockIdx.x * blockDim.x + threadIdx.x) >> 6;
    if (node >= N_NODES) return;
    int lane = threadIdx.x & 63;
    unsigned laneoff = lane * 4u;               // byte offset of this lane's half2
    float2 xrv  = __half22float2(((const __half2*)xrh)[(size_t)node * 64 + lane]);
    float2 attv = *(const float2*)&att_l[2 * lane];
    int beg = offsets[node], end = offsets[node + 1];
    float s = 0.f, accx = 0.f, accy = 0.f;
    const char* xlb = (const char*)xlh;
    for (int c0 = beg; c0 < end; c0 += 64) {
        int cnt = end - c0; if (cnt > 64) cnt = 64;
        int idx = sorted_src[c0 + (lane < cnt ? lane : cnt - 1)];   // coalesced
        unsigned off = (unsigned)idx << 8;       // byte offset of fp16 row (128*2B)
        int j = 0;
        for (; j + 8 <= cnt; j += 8) {
            unsigned o0 = __builtin_amdgcn_readlane(off, j)     + laneoff;
            unsigned o1 = __builtin_amdgcn_readlane(off, j + 1) + laneoff;
            unsigned o2 = __builtin_amdgcn_readlane(off, j + 2) + laneoff;
            unsigned o3 = __builtin_amdgcn_readlane(off, j + 3) + laneoff;
            unsigned o4 = __builtin_amdgcn_readlane(off, j + 4) + laneoff;
            unsigned o5 = __builtin_amdgcn_readlane(off, j + 5) + laneoff;
            unsigned o6 = __builtin_amdgcn_readlane(off, j + 6) + laneoff;
            unsigned o7 = __builtin_amdgcn_readlane(off, j + 7) + laneoff;
            float2 v0 = __half22float2(*(const __half2*)(xlb + o0));
            float2 v1 = __half22float2(*(const __half2*)(xlb + o1));
            float2 v2 = __half22float2(*(const __half2*)(xlb + o2));
            float2 v3 = __half22float2(*(const __half2*)(xlb + o3));
            float2 v4 = __half22float2(*(const __half2*)(xlb + o4));
            float2 v5 = __half22float2(*(const __half2*)(xlb + o5));
            float2 v6 = __half22float2(*(const __half2*)(xlb + o6));
            float2 v7 = __half22float2(*(const __half2*)(xlb + o7));
            float p0 = edge_logit(v0, xrv, attv);
            float p1 = edge_logit(v1, xrv, attv);
            float p2 = edge_logit(v2, xrv, attv);
            float p3 = edge_logit(v3, xrv, attv);
            float p4 = edge_logit(v4, xrv, attv);
            float p5 = edge_logit(v5, xrv, attv);
            float p6 = edge_logit(v6, xrv, attv);
            float p7 = edge_logit(v7, xrv, attv);
            p0 = head_reduce8(p0); p1 = head_reduce8(p1);
            p2 = head_reduce8(p2); p3 = head_reduce8(p3);
            p4 = head_reduce8(p4); p5 = head_reduce8(p5);
            p6 = head_reduce8(p6); p7 = head_reduce8(p7);
            float e0 = __expf(p0), e1 = __expf(p1);
            float e2 = __expf(p2), e3 = __expf(p3);
            float e4 = __expf(p4), e5 = __expf(p5);
            float e6 = __expf(p6), e7 = __expf(p7);
            s += ((e0 + e1) + (e2 + e3)) + ((e4 + e5) + (e6 + e7));
            accx = fmaf(e0, v0.x, accx); accy = fmaf(e0, v0.y, accy);
            accx = fmaf(e1, v1.x, accx); accy = fmaf(e1, v1.y, accy);
            accx = fmaf(e2, v2.x, accx); accy = fmaf(e2, v2.y, accy);
            accx = fmaf(e3, v3.x, accx); accy = fmaf(e3, v3.y, accy);
            accx = fmaf(e4, v4.x, accx); accy = fmaf(e4, v4.y, accy);
            accx = fmaf(e5, v5.x, accx); accy = fmaf(e5, v5.y, accy);
            accx = fmaf(e6, v6.x, accx); accy = fmaf(e6, v6.y, accy);
            accx = fmaf(e7, v7.x, accx); accy = fmaf(e7, v7.y, accy);
        }
        for (; j < cnt; ++j) {
            unsigned o0 = __builtin_amdgcn_readlane(off, j) + laneoff;
            float2 v0 = __half22float2(*(const __half2*)(xlb + o0));
            float p0 = edge_logit(v0, xrv, attv);
            p0 = head_reduce8(p0);
            float e0 = __expf(p0);
            s += e0;
            accx = fmaf(e0, v0.x, accx);
            accy = fmaf(e0, v0.y, accy);
        }
    }
    float inv = 1.f / s;                // every node has >=1 edge (self-loop)
    float2 bia = *(const float2*)&bias_l[2 * lane];
    float o0 = accx * inv + bia.x;
    float o1 = accy * inv + bia.y;
    float sum = o0 + o1, sq = o0 * o0 + o1 * o1;
    #pragma unroll
    for (int msk = 1; msk < 64; msk <<= 1) {
        sum += __shfl_xor(sum, msk);
        sq  += __shfl_xor(sq, msk);
    }
    float mu   = sum * (1.f / 128.f);
    float var  = sq * (1.f / 128.f) - mu * mu;
    float rstd = rsqrtf(var + LN_EPS);
    float2 gam = *(const float2*)&gamma_l[2 * lane];
    float2 bet = *(const float2*)&beta_l[2 * lane];
    float y0 = (o0 - mu) * rstd * gam.x + bet.x;
    float y1 = (o1 - mu) * rstd * gam.y + bet.y;
    y0 = y0 > 0.f ? y0 : __expf(y0) - 1.f;      // ELU (alpha=1)
    y1 = y1 > 0.f ? y1 : __expf(y1) - 1.f;
    size_t di = (size_t)node * D + 2 * lane;
    float2 hv = *(const float2*)&hin[di];
    hv.x += y0; hv.y += y1;
    *(float2*)&hout[di] = hv;
}

// ---------------------------------------------------------------------------

extern "C" void kernel_launch(void* const* d_in, const int* in_sizes, int n_in,
                              void* d_out, int out_size, void* d_ws, size_t ws_size,
                              hipStream_t stream) {
    const float* x     = (const float*)d_in[0];
    const float* Wl    = (const float*)d_in[1];
    const float* Wr    = (const float*)d_in[2];
    const float* att   = (const float*)d_in[3];
    const float* bias  = (const float*)d_in[4];
    const float* gamma = (const float*)d_in[5];
    const float* beta  = (const float*)d_in[6];
    const int*   ei    = (const int*)d_in[7];
    float* h = (float*)d_out;

    char* ws = (char*)d_ws;
    __half* xlh = (__half*)ws;       ws += (size_t)N_NODES * D * sizeof(__half);
    __half* xrh = (__half*)ws;       ws += (size_t)N_NODES * D * sizeof(__half);
    int* offsets = (int*)ws;         ws += (size_t)(N_NODES + 4) * sizeof(int);
    int* counts  = (int*)ws;         ws += (size_t)N_NODES * sizeof(int);
    int* bsum    = (int*)ws;         ws += 64 * sizeof(int);
    int* bpre    = (int*)ws;         ws += 64 * sizeof(int);
    int* sorted_src = (int*)ws;      // ETOT ints

    // CSR by dst (shared by all 3 layers)
    hipMemsetAsync(counts, 0, (size_t)N_NODES * sizeof(int), stream);
    hist_kernel<<<(ETOT + 255) / 256, 256, 0, stream>>>(ei, counts);
    scan1_kernel<<<SCAN_BLOCKS, 1024, 0, stream>>>(counts, offsets, bsum);
    scan2_kernel<<<1, 64, 0, stream>>>(bsum, bpre);
    scan3_kernel<<<SCAN_BLOCKS, 1024, 0, stream>>>(offsets, bpre);
    hipMemsetAsync(counts, 0, (size_t)N_NODES * sizeof(int), stream);  // reuse as cursor
    scatter_kernel<<<(ETOT + 255) / 256, 256, 0, stream>>>(ei, offsets, counts, sorted_src);

    dim3 ggrid((N_NODES + 63) / 64, 2);
    for (int l = 0; l < L; ++l) {
        const float* hin = (l == 0) ? x : h;
        gemm_half_kernel<<<ggrid, 512, 0, stream>>>(
            hin, Wl + (size_t)l * D * D, Wr + (size_t)l * D * D, xlh, xrh);
        gat_node_kernel<<<(N_NODES * 64 + 255) / 256, 256, 0, stream>>>(
            xlh, xrh, offsets, sorted_src,
            att + (size_t)l * D, bias + (size_t)l * D,
            gamma + (size_t)l * D, beta + (size_t)l * D, hin, h);
    }
}

// Round 5
// 371.524 us; speedup vs baseline: 2.0198x; 1.2209x over previous
//
#include <hip/hip_runtime.h>
#include <hip/hip_fp16.h>
#include <math.h>

#define N_NODES 50000
#define N_EDGES 800000
#define D 128
#define L 3
#define SLOPE 0.2f
#define LN_EPS 1e-5f
#define ETOT (N_EDGES + N_NODES)
#define SCAN_BLOCKS ((N_NODES + 1023) / 1024)   // 49

typedef _Float16 half8 __attribute__((ext_vector_type(8)));
typedef float f32x4 __attribute__((ext_vector_type(4)));

// ---------------- CSR build (once per call, reused for all layers) ----------

__global__ void hist_kernel(const int* __restrict__ ei, int* __restrict__ counts) {
    int idx = blockIdx.x * blockDim.x + threadIdx.x;
    if (idx >= ETOT) return;
    int d = (idx < N_EDGES) ? ei[N_EDGES + idx] : (idx - N_EDGES);
    atomicAdd(&counts[d], 1);
}

__global__ __launch_bounds__(1024) void scan1_kernel(const int* __restrict__ counts,
                                                     int* __restrict__ offsets,
                                                     int* __restrict__ bsum) {
    __shared__ int wsum[16];
    int tid = threadIdx.x;
    int lane = tid & 63, w = tid >> 6;
    int i = blockIdx.x * 1024 + tid;
    int v = (i < N_NODES) ? counts[i] : 0;
    int sc = v;
    #pragma unroll
    for (int off = 1; off < 64; off <<= 1) {
        int u = __shfl_up(sc, off);
        if (lane >= off) sc += u;
    }
    if (lane == 63) wsum[w] = sc;
    __syncthreads();
    if (w == 0) {
        int t2 = (lane < 16) ? wsum[lane] : 0;
        #pragma unroll
        for (int off = 1; off < 16; off <<= 1) {
            int u = __shfl_up(t2, off);
            if (lane >= off) t2 += u;
        }
        if (lane < 16) wsum[lane] = t2;
    }
    __syncthreads();
    int wpref = (w == 0) ? 0 : wsum[w - 1];
    if (i < N_NODES) offsets[i] = wpref + sc - v;      // block-local exclusive
    if (tid == 0) bsum[blockIdx.x] = wsum[15];
}

__global__ __launch_bounds__(64) void scan2_kernel(const int* __restrict__ bsum,
                                                   int* __restrict__ bpre) {
    int lane = threadIdx.x;
    int v = (lane < SCAN_BLOCKS) ? bsum[lane] : 0;
    int sc = v;
    #pragma unroll
    for (int off = 1; off < 64; off <<= 1) {
        int u = __shfl_up(sc, off);
        if (lane >= off) sc += u;
    }
    if (lane < SCAN_BLOCKS) bpre[lane] = sc - v;       // exclusive
}

__global__ __launch_bounds__(1024) void scan3_kernel(int* __restrict__ offsets,
                                                     const int* __restrict__ bpre) {
    int i = blockIdx.x * 1024 + threadIdx.x;
    if (i < N_NODES) offsets[i] += bpre[blockIdx.x];
    if (i == 0) offsets[N_NODES] = ETOT;
}

__global__ void scatter_kernel(const int* __restrict__ ei, const int* __restrict__ offsets,
                               int* __restrict__ cursor, int* __restrict__ sorted_src) {
    int idx = blockIdx.x * blockDim.x + threadIdx.x;
    if (idx >= ETOT) return;
    int s, d;
    if (idx < N_EDGES) { s = ei[idx]; d = ei[N_EDGES + idx]; }
    else               { s = d = idx - N_EDGES; }
    int pos = offsets[d] + atomicAdd(&cursor[d], 1);
    sorted_src[pos] = s;
}

// ---------------- W -> fp16 MFMA B-fragment precompute ---------------------
// Wfrag[l][y][kt][nt][lane][j]  (half8 per (l,y,kt,nt,lane))
// element = W[k = kt*32 + (lane>>4)*8 + j][n = nt*16 + (lane&15)]

__global__ __launch_bounds__(256) void wfrag_kernel(const float* __restrict__ Wl,
                                                    const float* __restrict__ Wr,
                                                    _Float16* __restrict__ Wfrag) {
    int u = blockIdx.x * 256 + threadIdx.x;   // 3*2*4*8*64 = 12288 slots
    if (u >= 3 * 4096) return;
    int lane = u & 63, nt = (u >> 6) & 7, kt = (u >> 9) & 3, y = (u >> 11) & 1, l = u >> 12;
    int r = lane & 15, q = lane >> 4;
    const float* W = (y ? Wr : Wl) + (size_t)l * D * D;
    half8 v;
    #pragma unroll
    for (int j = 0; j < 8; ++j)
        v[j] = (_Float16)W[(kt * 32 + q * 8 + j) * D + nt * 16 + r];
    *(half8*)&Wfrag[(size_t)u * 8] = v;
}

// ---------------- MFMA GEMM: out_fp16 = h @ W  -----------------------------
// block = 4 waves; tile M=64 (wave w -> rows 16w..16w+15), N=128, K=128.
// A staged fp32->fp16 into LDS in A-fragment order, linear lane addressing.
// B frags streamed from global (L2-hot, lane-contiguous dwordx4).

__global__ __launch_bounds__(256) void gemm_mfma_kernel(
        const float* __restrict__ h, const _Float16* __restrict__ WfragL,
        _Float16* __restrict__ xlh, _Float16* __restrict__ xrh) {
    __shared__ half8 Afrag[1024];   // [mt][kt][lane], 16 KB
    int t = threadIdx.x;
    int row0 = blockIdx.x * 64;
    #pragma unroll
    for (int i = 0; i < 4; ++i) {
        // frag slot = i*256 + t : mt=i, kt=t>>6, q=(t>>4)&3, r=t&15
        int kt = t >> 6, q = (t >> 4) & 3, r = t & 15;
        int row = row0 + i * 16 + r;
        int kc = kt * 4 + q;                  // 8-half chunk index
        float4 f0 = make_float4(0.f, 0.f, 0.f, 0.f), f1 = f0;
        if (row < N_NODES) {
            const float* p = &h[(size_t)row * D + kc * 8];
            f0 = *(const float4*)p;
            f1 = *(const float4*)(p + 4);
        }
        half8 v;
        v[0] = (_Float16)f0.x; v[1] = (_Float16)f0.y;
        v[2] = (_Float16)f0.z; v[3] = (_Float16)f0.w;
        v[4] = (_Float16)f1.x; v[5] = (_Float16)f1.y;
        v[6] = (_Float16)f1.z; v[7] = (_Float16)f1.w;
        Afrag[i * 256 + t] = v;               // linear: conflict-floor only
    }
    __syncthreads();
    const _Float16* Bf = WfragL + (size_t)blockIdx.y * 2048 * 8;
    int w = t >> 6, lane = t & 63;
    f32x4 acc[8];
    #pragma unroll
    for (int nt = 0; nt < 8; ++nt) acc[nt] = (f32x4){0.f, 0.f, 0.f, 0.f};
    #pragma unroll
    for (int kt = 0; kt < 4; ++kt) {
        half8 a = Afrag[(w * 4 + kt) * 64 + lane];
        #pragma unroll
        for (int nt = 0; nt < 8; ++nt) {
            half8 b = *(const half8*)&Bf[(size_t)((kt * 8 + nt) * 64 + lane) * 8];
            acc[nt] = __builtin_amdgcn_mfma_f32_16x16x32_f16(a, b, acc[nt], 0, 0, 0);
        }
    }
    _Float16* out = blockIdx.y ? xrh : xlh;
    int rq = lane >> 4, rc = lane & 15;
    int rbase = row0 + w * 16 + rq * 4;       // C/D: col=lane&15, row=(lane>>4)*4+reg
    #pragma unroll
    for (int nt = 0; nt < 8; ++nt) {
        #pragma unroll
        for (int reg = 0; reg < 4; ++reg) {
            int row = rbase + reg;
            if (row < N_NODES)
                out[(size_t)row * D + nt * 16 + rc] = (_Float16)acc[nt][reg];
        }
    }
}

// ---------------- per-node GATv2 + softmax + LN + ELU + residual -----------

__device__ __forceinline__ float head_reduce8(float p) {
    int t;
    t = __builtin_amdgcn_update_dpp(0, __float_as_int(p), 0xB1, 0xF, 0xF, true);  // xor 1
    p += __int_as_float(t);
    t = __builtin_amdgcn_update_dpp(0, __float_as_int(p), 0x4E, 0xF, 0xF, true);  // xor 2
    p += __int_as_float(t);
    t = __builtin_amdgcn_update_dpp(0, __float_as_int(p), 0x141, 0xF, 0xF, true); // xor 4
    p += __int_as_float(t);
    return p;
}

__device__ __forceinline__ float leaky(float f) { return fmaxf(f, SLOPE * f); }

__device__ __forceinline__ float edge_logit(float2 v, float2 xrv, float2 attv) {
    return fmaf(leaky(v.x + xrv.x), attv.x, leaky(v.y + xrv.y) * attv.y);
}

__global__ __launch_bounds__(256) void gat_node_kernel(
        const __half* __restrict__ xlh, const __half* __restrict__ xrh,
        const int* __restrict__ offsets, const int* __restrict__ sorted_src,
        const float* __restrict__ att_l, const float* __restrict__ bias_l,
        const float* __restrict__ gamma_l, const float* __restrict__ beta_l,
        const float* __restrict__ hin, float* __restrict__ hout) {
    int node = (blockIdx.x * blockDim.x + threadIdx.x) >> 6;
    if (node >= N_NODES) return;
    int lane = threadIdx.x & 63;
    unsigned laneoff = lane * 4u;               // byte offset of this lane's half2
    float2 xrv  = __half22float2(((const __half2*)xrh)[(size_t)node * 64 + lane]);
    float2 attv = *(const float2*)&att_l[2 * lane];
    int beg = offsets[node], end = offsets[node + 1];
    float s = 0.f, accx = 0.f, accy = 0.f;
    const char* xlb = (const char*)xlh;
    for (int c0 = beg; c0 < end; c0 += 64) {
        int cnt = end - c0; if (cnt > 64) cnt = 64;
        int idx = sorted_src[c0 + (lane < cnt ? lane : cnt - 1)];   // coalesced
        unsigned off = (unsigned)idx << 8;       // byte offset of fp16 row (128*2B)
        int j = 0;
        for (; j + 8 <= cnt; j += 8) {
            unsigned o0 = __builtin_amdgcn_readlane(off, j)     + laneoff;
            unsigned o1 = __builtin_amdgcn_readlane(off, j + 1) + laneoff;
            unsigned o2 = __builtin_amdgcn_readlane(off, j + 2) + laneoff;
            unsigned o3 = __builtin_amdgcn_readlane(off, j + 3) + laneoff;
            unsigned o4 = __builtin_amdgcn_readlane(off, j + 4) + laneoff;
            unsigned o5 = __builtin_amdgcn_readlane(off, j + 5) + laneoff;
            unsigned o6 = __builtin_amdgcn_readlane(off, j + 6) + laneoff;
            unsigned o7 = __builtin_amdgcn_readlane(off, j + 7) + laneoff;
            float2 v0 = __half22float2(*(const __half2*)(xlb + o0));
            float2 v1 = __half22float2(*(const __half2*)(xlb + o1));
            float2 v2 = __half22float2(*(const __half2*)(xlb + o2));
            float2 v3 = __half22float2(*(const __half2*)(xlb + o3));
            float2 v4 = __half22float2(*(const __half2*)(xlb + o4));
            float2 v5 = __half22float2(*(const __half2*)(xlb + o5));
            float2 v6 = __half22float2(*(const __half2*)(xlb + o6));
            float2 v7 = __half22float2(*(const __half2*)(xlb + o7));
            float p0 = edge_logit(v0, xrv, attv);
            float p1 = edge_logit(v1, xrv, attv);
            float p2 = edge_logit(v2, xrv, attv);
            float p3 = edge_logit(v3, xrv, attv);
            float p4 = edge_logit(v4, xrv, attv);
            float p5 = edge_logit(v5, xrv, attv);
            float p6 = edge_logit(v6, xrv, attv);
            float p7 = edge_logit(v7, xrv, attv);
            p0 = head_reduce8(p0); p1 = head_reduce8(p1);
            p2 = head_reduce8(p2); p3 = head_reduce8(p3);
            p4 = head_reduce8(p4); p5 = head_reduce8(p5);
            p6 = head_reduce8(p6); p7 = head_reduce8(p7);
            float e0 = __expf(p0), e1 = __expf(p1);
            float e2 = __expf(p2), e3 = __expf(p3);
            float e4 = __expf(p4), e5 = __expf(p5);
            float e6 = __expf(p6), e7 = __expf(p7);
            s += ((e0 + e1) + (e2 + e3)) + ((e4 + e5) + (e6 + e7));
            accx = fmaf(e0, v0.x, accx); accy = fmaf(e0, v0.y, accy);
            accx = fmaf(e1, v1.x, accx); accy = fmaf(e1, v1.y, accy);
            accx = fmaf(e2, v2.x, accx); accy = fmaf(e2, v2.y, accy);
            accx = fmaf(e3, v3.x, accx); accy = fmaf(e3, v3.y, accy);
            accx = fmaf(e4, v4.x, accx); accy = fmaf(e4, v4.y, accy);
            accx = fmaf(e5, v5.x, accx); accy = fmaf(e5, v5.y, accy);
            accx = fmaf(e6, v6.x, accx); accy = fmaf(e6, v6.y, accy);
            accx = fmaf(e7, v7.x, accx); accy = fmaf(e7, v7.y, accy);
        }
        for (; j < cnt; ++j) {
            unsigned o0 = __builtin_amdgcn_readlane(off, j) + laneoff;
            float2 v0 = __half22float2(*(const __half2*)(xlb + o0));
            float p0 = edge_logit(v0, xrv, attv);
            p0 = head_reduce8(p0);
            float e0 = __expf(p0);
            s += e0;
            accx = fmaf(e0, v0.x, accx);
            accy = fmaf(e0, v0.y, accy);
        }
    }
    float inv = 1.f / s;                // every node has >=1 edge (self-loop)
    float2 bia = *(const float2*)&bias_l[2 * lane];
    float o0 = accx * inv + bia.x;
    float o1 = accy * inv + bia.y;
    float sum = o0 + o1, sq = o0 * o0 + o1 * o1;
    #pragma unroll
    for (int msk = 1; msk < 64; msk <<= 1) {
        sum += __shfl_xor(sum, msk);
        sq  += __shfl_xor(sq, msk);
    }
    float mu   = sum * (1.f / 128.f);
    float var  = sq * (1.f / 128.f) - mu * mu;
    float rstd = rsqrtf(var + LN_EPS);
    float2 gam = *(const float2*)&gamma_l[2 * lane];
    float2 bet = *(const float2*)&beta_l[2 * lane];
    float y0 = (o0 - mu) * rstd * gam.x + bet.x;
    float y1 = (o1 - mu) * rstd * gam.y + bet.y;
    y0 = y0 > 0.f ? y0 : __expf(y0) - 1.f;      // ELU (alpha=1)
    y1 = y1 > 0.f ? y1 : __expf(y1) - 1.f;
    size_t di = (size_t)node * D + 2 * lane;
    float2 hv = *(const float2*)&hin[di];
    hv.x += y0; hv.y += y1;
    *(float2*)&hout[di] = hv;
}

// ---------------------------------------------------------------------------

extern "C" void kernel_launch(void* const* d_in, const int* in_sizes, int n_in,
                              void* d_out, int out_size, void* d_ws, size_t ws_size,
                              hipStream_t stream) {
    const float* x     = (const float*)d_in[0];
    const float* Wl    = (const float*)d_in[1];
    const float* Wr    = (const float*)d_in[2];
    const float* att   = (const float*)d_in[3];
    const float* bias  = (const float*)d_in[4];
    const float* gamma = (const float*)d_in[5];
    const float* beta  = (const float*)d_in[6];
    const int*   ei    = (const int*)d_in[7];
    float* h = (float*)d_out;

    char* ws = (char*)d_ws;
    _Float16* xlh = (_Float16*)ws;   ws += (size_t)N_NODES * D * sizeof(_Float16);
    _Float16* xrh = (_Float16*)ws;   ws += (size_t)N_NODES * D * sizeof(_Float16);
    _Float16* Wfrag = (_Float16*)ws; ws += (size_t)3 * 4096 * 8 * sizeof(_Float16);
    int* offsets = (int*)ws;         ws += (size_t)(N_NODES + 4) * sizeof(int);
    int* counts  = (int*)ws;         ws += (size_t)N_NODES * sizeof(int);
    int* bsum    = (int*)ws;         ws += 64 * sizeof(int);
    int* bpre    = (int*)ws;         ws += 64 * sizeof(int);
    int* sorted_src = (int*)ws;      // ETOT ints

    // W fragments (all layers) + CSR by dst (shared by all 3 layers)
    wfrag_kernel<<<48, 256, 0, stream>>>(Wl, Wr, Wfrag);
    hipMemsetAsync(counts, 0, (size_t)N_NODES * sizeof(int), stream);
    hist_kernel<<<(ETOT + 255) / 256, 256, 0, stream>>>(ei, counts);
    scan1_kernel<<<SCAN_BLOCKS, 1024, 0, stream>>>(counts, offsets, bsum);
    scan2_kernel<<<1, 64, 0, stream>>>(bsum, bpre);
    scan3_kernel<<<SCAN_BLOCKS, 1024, 0, stream>>>(offsets, bpre);
    hipMemsetAsync(counts, 0, (size_t)N_NODES * sizeof(int), stream);  // reuse as cursor
    scatter_kernel<<<(ETOT + 255) / 256, 256, 0, stream>>>(ei, offsets, counts, sorted_src);

    dim3 ggrid((N_NODES + 63) / 64, 2);
    for (int l = 0; l < L; ++l) {
        const float* hin = (l == 0) ? x : h;
        gemm_mfma_kernel<<<ggrid, 256, 0, stream>>>(
            hin, Wfrag + (size_t)l * 4096 * 8, xlh, xrh);
        gat_node_kernel<<<(N_NODES * 64 + 255) / 256, 256, 0, stream>>>(
            (const __half*)xlh, (const __half*)xrh, offsets, sorted_src,
            att + (size_t)l * D, bias + (size_t)l * D,
            gamma + (size_t)l * D, beta + (size_t)l * D, hin, h);
    }
}

// Round 7
// 340.159 us; speedup vs baseline: 2.2061x; 1.0922x over previous
//
#include <hip/hip_runtime.h>
#include <hip/hip_fp16.h>
#include <math.h>

#define N_NODES 50000
#define N_EDGES 800000
#define D 128
#define L 3
#define SLOPE 0.2f
#define LN_EPS 1e-5f
#define ETOT (N_EDGES + N_NODES)
#define SCAN_BLOCKS ((N_NODES + 1023) / 1024)   // 49

typedef _Float16 half8 __attribute__((ext_vector_type(8)));
typedef _Float16 h2v  __attribute__((ext_vector_type(2)));
typedef float f32x4 __attribute__((ext_vector_type(4)));

// ---------------- CSR build (once per call, reused for all layers) ----------
// hist pass also records each edge's rank within its dst (atomic returns old),
// so the placement pass needs no atomics and writes u16 src ids.

__global__ void rank_hist_kernel(const int* __restrict__ ei, int* __restrict__ counts,
                                 int* __restrict__ rank) {
    int idx = blockIdx.x * blockDim.x + threadIdx.x;
    if (idx >= ETOT) return;
    int d = (idx < N_EDGES) ? ei[N_EDGES + idx] : (idx - N_EDGES);
    rank[idx] = atomicAdd(&counts[d], 1);
}

__global__ __launch_bounds__(1024) void scan1_kernel(const int* __restrict__ counts,
                                                     int* __restrict__ offsets,
                                                     int* __restrict__ bsum) {
    __shared__ int wsum[16];
    int tid = threadIdx.x;
    int lane = tid & 63, w = tid >> 6;
    int i = blockIdx.x * 1024 + tid;
    int v = (i < N_NODES) ? counts[i] : 0;
    int sc = v;
    #pragma unroll
    for (int off = 1; off < 64; off <<= 1) {
        int u = __shfl_up(sc, off);
        if (lane >= off) sc += u;
    }
    if (lane == 63) wsum[w] = sc;
    __syncthreads();
    if (w == 0) {
        int t2 = (lane < 16) ? wsum[lane] : 0;
        #pragma unroll
        for (int off = 1; off < 16; off <<= 1) {
            int u = __shfl_up(t2, off);
            if (lane >= off) t2 += u;
        }
        if (lane < 16) wsum[lane] = t2;
    }
    __syncthreads();
    int wpref = (w == 0) ? 0 : wsum[w - 1];
    if (i < N_NODES) offsets[i] = wpref + sc - v;      // block-local exclusive
    if (tid == 0) bsum[blockIdx.x] = wsum[15];
}

__global__ __launch_bounds__(64) void scan2_kernel(const int* __restrict__ bsum,
                                                   int* __restrict__ bpre) {
    int lane = threadIdx.x;
    int v = (lane < SCAN_BLOCKS) ? bsum[lane] : 0;
    int sc = v;
    #pragma unroll
    for (int off = 1; off < 64; off <<= 1) {
        int u = __shfl_up(sc, off);
        if (lane >= off) sc += u;
    }
    if (lane < SCAN_BLOCKS) bpre[lane] = sc - v;       // exclusive
}

__global__ __launch_bounds__(1024) void scan3_kernel(int* __restrict__ offsets,
                                                     const int* __restrict__ bpre) {
    int i = blockIdx.x * 1024 + threadIdx.x;
    if (i < N_NODES) offsets[i] += bpre[blockIdx.x];
    if (i == 0) offsets[N_NODES] = ETOT;
}

__global__ void scatter_kernel(const int* __restrict__ ei, const int* __restrict__ offsets,
                               const int* __restrict__ rank,
                               unsigned short* __restrict__ sorted16) {
    int idx = blockIdx.x * blockDim.x + threadIdx.x;
    if (idx >= ETOT) return;
    int s, d;
    if (idx < N_EDGES) { s = ei[idx]; d = ei[N_EDGES + idx]; }
    else               { s = d = idx - N_EDGES; }
    sorted16[offsets[d] + rank[idx]] = (unsigned short)s;   // no atomic
}

// ---------------- W -> fp16 MFMA B-fragment precompute ---------------------
// Wfrag[l][y][kt][nt][lane][j]; element = W[kt*32+(lane>>4)*8+j][nt*16+(lane&15)]

__global__ __launch_bounds__(256) void wfrag_kernel(const float* __restrict__ Wl,
                                                    const float* __restrict__ Wr,
                                                    _Float16* __restrict__ Wfrag) {
    int u = blockIdx.x * 256 + threadIdx.x;   // 3*2*4*8*64 = 12288 slots
    if (u >= 3 * 4096) return;
    int lane = u & 63, nt = (u >> 6) & 7, kt = (u >> 9) & 3, y = (u >> 11) & 1, l = u >> 12;
    int r = lane & 15, q = lane >> 4;
    const float* W = (y ? Wr : Wl) + (size_t)l * D * D;
    half8 v;
    #pragma unroll
    for (int j = 0; j < 8; ++j)
        v[j] = (_Float16)W[(kt * 32 + q * 8 + j) * D + nt * 16 + r];
    *(half8*)&Wfrag[(size_t)u * 8] = v;
}

// ---------------- MFMA GEMM: xl,xr (fp16) = h @ {Wl,Wr} --------------------
// block = 4 waves; tile M=64, N=256 (both W in one block -> h staged ONCE).

__global__ __launch_bounds__(256) void gemm_mfma_kernel(
        const float* __restrict__ h, const _Float16* __restrict__ WfragL,
        _Float16* __restrict__ xlh, _Float16* __restrict__ xrh) {
    __shared__ half8 Afrag[1024];   // [mt][kt][lane], 16 KB
    int t = threadIdx.x;
    int row0 = blockIdx.x * 64;
    {
        int kt = t >> 6, q = (t >> 4) & 3, r = t & 15;
        int kc = kt * 4 + q;                  // 8-half chunk index
        #pragma unroll
        for (int i = 0; i < 4; ++i) {
            int row = row0 + i * 16 + r;
            float4 f0 = make_float4(0.f, 0.f, 0.f, 0.f), f1 = f0;
            if (row < N_NODES) {
                const float* p = &h[(size_t)row * D + kc * 8];
                f0 = *(const float4*)p;
                f1 = *(const float4*)(p + 4);
            }
            half8 v;
            v[0] = (_Float16)f0.x; v[1] = (_Float16)f0.y;
            v[2] = (_Float16)f0.z; v[3] = (_Float16)f0.w;
            v[4] = (_Float16)f1.x; v[5] = (_Float16)f1.y;
            v[6] = (_Float16)f1.z; v[7] = (_Float16)f1.w;
            Afrag[i * 256 + t] = v;           // linear lanes: conflict-floor
        }
    }
    __syncthreads();
    int w = t >> 6, lane = t & 63;
    f32x4 acc[16];
    #pragma unroll
    for (int i = 0; i < 16; ++i) acc[i] = (f32x4){0.f, 0.f, 0.f, 0.f};
    #pragma unroll
    for (int kt = 0; kt < 4; ++kt) {
        half8 a = Afrag[(w * 4 + kt) * 64 + lane];
        #pragma unroll
        for (int y = 0; y < 2; ++y) {
            #pragma unroll
            for (int nt = 0; nt < 8; ++nt) {
                half8 b = *(const half8*)&WfragL[(size_t)(((y * 4 + kt) * 8 + nt) * 64 + lane) * 8];
                acc[y * 8 + nt] = __builtin_amdgcn_mfma_f32_16x16x32_f16(a, b, acc[y * 8 + nt], 0, 0, 0);
            }
        }
    }
    int rq = lane >> 4, rc = lane & 15;
    int rbase = row0 + w * 16 + rq * 4;       // C/D: col=lane&15, row=(lane>>4)*4+reg
    #pragma unroll
    for (int y = 0; y < 2; ++y) {
        _Float16* out = y ? xrh : xlh;
        #pragma unroll
        for (int nt = 0; nt < 8; ++nt) {
            #pragma unroll
            for (int reg = 0; reg < 4; ++reg) {
                int row = rbase + reg;
                if (row < N_NODES)
                    out[(size_t)row * D + nt * 16 + rc] = (_Float16)acc[y * 8 + nt][reg];
            }
        }
    }
}

// ---------------- per-node GATv2 + softmax + LN + ELU + residual -----------
// one wave per node; lane holds channels {2*lane, 2*lane+1}; head = lane>>3.
// Packed-fp16 logit path (v_pk_add/mul/max + v_dot2_f32_f16); att pre-scaled
// by log2(e) so softmax exp is a bare v_exp_f32. DPP 8-lane head reduction.

__device__ __forceinline__ float head_reduce8(float p) {
    int t;
    t = __builtin_amdgcn_update_dpp(0, __float_as_int(p), 0xB1, 0xF, 0xF, true);  // xor 1
    p += __int_as_float(t);
    t = __builtin_amdgcn_update_dpp(0, __float_as_int(p), 0x4E, 0xF, 0xF, true);  // xor 2
    p += __int_as_float(t);
    t = __builtin_amdgcn_update_dpp(0, __float_as_int(p), 0x141, 0xF, 0xF, true); // half-mirror
    p += __int_as_float(t);
    return p;
}

__device__ __forceinline__ float logit2(h2v v, h2v xrv2, h2v att2, h2v slope2) {
    h2v f  = v + xrv2;                                   // v_pk_add_f16
    h2v lf = __builtin_elementwise_max(f, f * slope2);   // v_pk_max/mul_f16
    return __builtin_amdgcn_fdot2(lf, att2, 0.f, false); // v_dot2_f32_f16
}

__device__ __forceinline__ float2 h2f(h2v v) {
    return make_float2((float)v[0], (float)v[1]);
}

__global__ __launch_bounds__(256) void gat_node_kernel(
        const _Float16* __restrict__ xlh, const _Float16* __restrict__ xrh,
        const int* __restrict__ offsets, const unsigned short* __restrict__ sorted16,
        const float* __restrict__ att_l, const float* __restrict__ bias_l,
        const float* __restrict__ gamma_l, const float* __restrict__ beta_l,
        const float* __restrict__ hin, float* __restrict__ hout) {
    int node = (blockIdx.x * blockDim.x + threadIdx.x) >> 6;
    if (node >= N_NODES) return;
    int lane = threadIdx.x & 63;
    unsigned laneoff = lane * 4u;               // byte offset of this lane's half2
    h2v xrv2 = ((const h2v*)xrh)[(size_t)node * 64 + lane];
    float2 attf = *(const float2*)&att_l[2 * lane];
    h2v att2;
    att2[0] = (_Float16)(attf.x * 1.44269504f);
    att2[1] = (_Float16)(attf.y * 1.44269504f);
    h2v slope2;
    slope2[0] = (_Float16)SLOPE;
    slope2[1] = (_Float16)SLOPE;
    int beg = offsets[node], end = offsets[node + 1];
    float s = 0.f, accx = 0.f, accy = 0.f;
    const char* xlb = (const char*)xlh;
    for (int c0 = beg; c0 < end; c0 += 64) {
        int cnt = end - c0; if (cnt > 64) cnt = 64;
        unsigned idx = sorted16[c0 + (lane < cnt ? lane : cnt - 1)];   // coalesced u16
        unsigned off = idx << 8;                 // byte offset of fp16 row (128*2B)
        int j = 0;
        for (; j + 8 <= cnt; j += 8) {
            unsigned o0 = __builtin_amdgcn_readlane(off, j)     + laneoff;
            unsigned o1 = __builtin_amdgcn_readlane(off, j + 1) + laneoff;
            unsigned o2 = __builtin_amdgcn_readlane(off, j + 2) + laneoff;
            unsigned o3 = __builtin_amdgcn_readlane(off, j + 3) + laneoff;
            unsigned o4 = __builtin_amdgcn_readlane(off, j + 4) + laneoff;
            unsigned o5 = __builtin_amdgcn_readlane(off, j + 5) + laneoff;
            unsigned o6 = __builtin_amdgcn_readlane(off, j + 6) + laneoff;
            unsigned o7 = __builtin_amdgcn_readlane(off, j + 7) + laneoff;
            h2v v0 = *(const h2v*)(xlb + o0);
            h2v v1 = *(const h2v*)(xlb + o1);
            h2v v2 = *(const h2v*)(xlb + o2);
            h2v v3 = *(const h2v*)(xlb + o3);
            h2v v4 = *(const h2v*)(xlb + o4);
            h2v v5 = *(const h2v*)(xlb + o5);
            h2v v6 = *(const h2v*)(xlb + o6);
            h2v v7 = *(const h2v*)(xlb + o7);
            float p0 = logit2(v0, xrv2, att2, slope2);
            float p1 = logit2(v1, xrv2, att2, slope2);
            float p2 = logit2(v2, xrv2, att2, slope2);
            float p3 = logit2(v3, xrv2, att2, slope2);
            float p4 = logit2(v4, xrv2, att2, slope2);
            float p5 = logit2(v5, xrv2, att2, slope2);
            float p6 = logit2(v6, xrv2, att2, slope2);
            float p7 = logit2(v7, xrv2, att2, slope2);
            p0 = head_reduce8(p0); p1 = head_reduce8(p1);
            p2 = head_reduce8(p2); p3 = head_reduce8(p3);
            p4 = head_reduce8(p4); p5 = head_reduce8(p5);
            p6 = head_reduce8(p6); p7 = head_reduce8(p7);
            float e0 = __builtin_amdgcn_exp2f(p0), e1 = __builtin_amdgcn_exp2f(p1);
            float e2 = __builtin_amdgcn_exp2f(p2), e3 = __builtin_amdgcn_exp2f(p3);
            float e4 = __builtin_amdgcn_exp2f(p4), e5 = __builtin_amdgcn_exp2f(p5);
            float e6 = __builtin_amdgcn_exp2f(p6), e7 = __builtin_amdgcn_exp2f(p7);
            s += ((e0 + e1) + (e2 + e3)) + ((e4 + e5) + (e6 + e7));
            float2 f0 = h2f(v0), f1 = h2f(v1);
            float2 f2 = h2f(v2), f3 = h2f(v3);
            float2 f4 = h2f(v4), f5 = h2f(v5);
            float2 f6 = h2f(v6), f7 = h2f(v7);
            accx = fmaf(e0, f0.x, accx); accy = fmaf(e0, f0.y, accy);
            accx = fmaf(e1, f1.x, accx); accy = fmaf(e1, f1.y, accy);
            accx = fmaf(e2, f2.x, accx); accy = fmaf(e2, f2.y, accy);
            accx = fmaf(e3, f3.x, accx); accy = fmaf(e3, f3.y, accy);
            accx = fmaf(e4, f4.x, accx); accy = fmaf(e4, f4.y, accy);
            accx = fmaf(e5, f5.x, accx); accy = fmaf(e5, f5.y, accy);
            accx = fmaf(e6, f6.x, accx); accy = fmaf(e6, f6.y, accy);
            accx = fmaf(e7, f7.x, accx); accy = fmaf(e7, f7.y, accy);
        }
        for (; j < cnt; ++j) {
            unsigned o0 = __builtin_amdgcn_readlane(off, j) + laneoff;
            h2v v0 = *(const h2v*)(xlb + o0);
            float p0 = logit2(v0, xrv2, att2, slope2);
            p0 = head_reduce8(p0);
            float e0 = __builtin_amdgcn_exp2f(p0);
            s += e0;
            float2 f0 = h2f(v0);
            accx = fmaf(e0, f0.x, accx);
            accy = fmaf(e0, f0.y, accy);
        }
    }
    float inv = 1.f / s;                // every node has >=1 edge (self-loop)
    float2 bia = *(const float2*)&bias_l[2 * lane];
    float o0 = accx * inv + bia.x;
    float o1 = accy * inv + bia.y;
    float sum = o0 + o1, sq = o0 * o0 + o1 * o1;
    #pragma unroll
    for (int msk = 1; msk < 64; msk <<= 1) {
        sum += __shfl_xor(sum, msk);
        sq  += __shfl_xor(sq, msk);
    }
    float mu   = sum * (1.f / 128.f);
    float var  = sq * (1.f / 128.f) - mu * mu;
    float rstd = rsqrtf(var + LN_EPS);
    float2 gam = *(const float2*)&gamma_l[2 * lane];
    float2 bet = *(const float2*)&beta_l[2 * lane];
    float y0 = (o0 - mu) * rstd * gam.x + bet.x;
    float y1 = (o1 - mu) * rstd * gam.y + bet.y;
    y0 = y0 > 0.f ? y0 : __expf(y0) - 1.f;      // ELU (alpha=1)
    y1 = y1 > 0.f ? y1 : __expf(y1) - 1.f;
    size_t di = (size_t)node * D + 2 * lane;
    float2 hv = *(const float2*)&hin[di];
    hv.x += y0; hv.y += y1;
    *(float2*)&hout[di] = hv;
}

// ---------------------------------------------------------------------------

extern "C" void kernel_launch(void* const* d_in, const int* in_sizes, int n_in,
                              void* d_out, int out_size, void* d_ws, size_t ws_size,
                              hipStream_t stream) {
    const float* x     = (const float*)d_in[0];
    const float* Wl    = (const float*)d_in[1];
    const float* Wr    = (const float*)d_in[2];
    const float* att   = (const float*)d_in[3];
    const float* bias  = (const float*)d_in[4];
    const float* gamma = (const float*)d_in[5];
    const float* beta  = (const float*)d_in[6];
    const int*   ei    = (const int*)d_in[7];
    float* h = (float*)d_out;

    char* ws = (char*)d_ws;
    _Float16* xlh = (_Float16*)ws;   ws += (size_t)N_NODES * D * sizeof(_Float16);
    _Float16* xrh = (_Float16*)ws;   ws += (size_t)N_NODES * D * sizeof(_Float16);
    _Float16* Wfrag = (_Float16*)ws; ws += (size_t)3 * 4096 * 8 * sizeof(_Float16);
    int* offsets = (int*)ws;         ws += (size_t)(N_NODES + 4) * sizeof(int);
    int* counts  = (int*)ws;         ws += (size_t)N_NODES * sizeof(int);
    int* bsum    = (int*)ws;         ws += 64 * sizeof(int);
    int* bpre    = (int*)ws;         ws += 64 * sizeof(int);
    int* rank    = (int*)ws;         ws += (size_t)ETOT * sizeof(int);
    unsigned short* sorted16 = (unsigned short*)ws;   // ETOT u16

    // W fragments (all layers) + CSR by dst (shared by all 3 layers)
    wfrag_kernel<<<48, 256, 0, stream>>>(Wl, Wr, Wfrag);
    (void)hipMemsetAsync(counts, 0, (size_t)N_NODES * sizeof(int), stream);
    rank_hist_kernel<<<(ETOT + 255) / 256, 256, 0, stream>>>(ei, counts, rank);
    scan1_kernel<<<SCAN_BLOCKS, 1024, 0, stream>>>(counts, offsets, bsum);
    scan2_kernel<<<1, 64, 0, stream>>>(bsum, bpre);
    scan3_kernel<<<SCAN_BLOCKS, 1024, 0, stream>>>(offsets, bpre);
    scatter_kernel<<<(ETOT + 255) / 256, 256, 0, stream>>>(ei, offsets, rank, sorted16);

    for (int l = 0; l < L; ++l) {
        const float* hin = (l == 0) ? x : h;
        gemm_mfma_kernel<<<(N_NODES + 63) / 64, 256, 0, stream>>>(
            hin, Wfrag + (size_t)l * 4096 * 8, xlh, xrh);
        gat_node_kernel<<<(N_NODES * 64 + 255) / 256, 256, 0, stream>>>(
            xlh, xrh, offsets, sorted16,
            att + (size_t)l * D, bias + (size_t)l * D,
            gamma + (size_t)l * D, beta + (size_t)l * D, hin, h);
    }
}